// Round 13
// baseline (126.793 us; speedup 1.0000x reference)
//
#include <hip/hip_runtime.h>

#define NDAYS 250
#define SCALING 12.0f
#define TPB 256
#define TILE 1024       // samples per q per tile; 4*TILE m's; TILE*5 floats per array per q
#define MAXROWS 512

typedef float f4 __attribute__((ext_vector_type(4)));
typedef int   i4 __attribute__((ext_vector_type(4)));

// Pi[d] = sum over k in [0,4N): w[k%N]*t_flat[k]*sigmoid(12*in_flat[k]) by date[k%N].
// k = 4i+j (sample-major), i = q*nq+ii -> m = 4*ii+j.
// Block owns ii-tile of TILE samples (all 4 q's). Thread t owns f4 chunks {256e+t, e<5}
// of the 5120-float tile -> input/target loads are lane-stride 16 B (8 L1 lines/wave-instr).
// w/d for the tile's 4096 m's are STAGED through LDS with coalesced dwordx4 loads, then
// per-element metadata comes from ds_read (lane stride ~3.2 floats => ~2-way, free).
// acc[5][4] accumulates t*sigmoid across q in registers; ONE LDS atomic per element.
// Invalid slots (resp col j==4, tile tail): weight=0, day=lane (adds 0.0, lane-distinct).
__global__ __launch_bounds__(TPB) void pi_kernel(
    const float* __restrict__ inputs, const float* __restrict__ targets,
    const float* __restrict__ weights, const int* __restrict__ date,
    float* __restrict__ part, int n) {
    __shared__ float sPi[NDAYS];
    __shared__ float sw[4 * TILE];
    __shared__ int   sd[4 * TILE];
    for (int i = threadIdx.x; i < NDAYS; i += TPB) sPi[i] = 0.0f;

    const int nq   = n >> 2;
    const int ii0  = blockIdx.x * TILE;       // grid sized so ii0 < nq always
    const int lane = threadIdx.x & 63;
    const int mb   = 4 * ii0;

    // stage tile weights/date: 4096 elements, TPB threads x 4 f4 each, coalesced
    #pragma unroll
    for (int e = 0; e < 4; ++e) {
        const int x = 4 * (TPB * e + threadIdx.x);
        f4 wv = {0.0f, 0.0f, 0.0f, 0.0f};
        i4 dv = {lane, lane, lane, lane};
        if (mb + x < n) {                      // n%4==0, x%4==0 => full f4 in-bounds
            wv = *(const f4*)(weights + mb + x);
            dv = *(const i4*)(date + mb + x);
        }
        *(f4*)&sw[x] = wv;
        *(i4*)&sd[x] = dv;
    }
    __syncthreads();

    const int ts  = min(TILE, nq - ii0);
    const int nfl = ts * 5;

    int   dy[5][4];
    float wt[5][4];
    #pragma unroll
    for (int e = 0; e < 5; ++e) {
        const int fl0 = 4 * (TPB * e + threadIdx.x);
        #pragma unroll
        for (int dlt = 0; dlt < 4; ++dlt) {
            const int fl = fl0 + dlt;
            const int si = (int)(((unsigned)fl * 52429u) >> 18);  // fl/5 exact for fl<5120
            const int j  = fl - 5 * si;
            const bool valid = (fl < nfl) && (j < 4);
            const int  mi = 4 * si + j;                           // m - mb
            wt[e][dlt] = valid ? sw[mi] : 0.0f;
            dy[e][dlt] = valid ? sd[mi] : lane;
        }
    }

    float acc[5][4] = {};
    #pragma unroll
    for (int q = 0; q < 4; ++q) {
        const size_t base = ((size_t)q * nq + ii0) * 5;           // 16B-aligned
        #pragma unroll
        for (int e = 0; e < 5; ++e) {
            const int fl0 = 4 * (TPB * e + threadIdx.x);
            f4 inv = {0.0f, 0.0f, 0.0f, 0.0f};
            f4 tgv = {0.0f, 0.0f, 0.0f, 0.0f};
            if (fl0 < nfl) {
                inv = *(const f4*)(inputs + base + fl0);
                tgv = *(const f4*)(targets + base + fl0);
            }
            #pragma unroll
            for (int dlt = 0; dlt < 4; ++dlt) {
                const float e1 = __expf(-SCALING * inv[dlt]);
                const float sg = __builtin_amdgcn_rcpf(1.0f + e1);
                acc[e][dlt] += tgv[dlt] * sg;
            }
        }
    }

    #pragma unroll
    for (int e = 0; e < 5; ++e)
        #pragma unroll
        for (int dlt = 0; dlt < 4; ++dlt)
            atomicAdd(&sPi[dy[e][dlt]], acc[e][dlt] * wt[e][dlt]);

    __syncthreads();
    float* row = part + (size_t)blockIdx.x * NDAYS;
    for (int i = threadIdx.x; i < NDAYS; i += TPB) row[i] = sPi[i];
}

// 1 block, 1024 threads: Pi[c] = sum over nrows of part[r][c] (4-way row split, coalesced
// across c), LDS-combine, then loss.
__global__ __launch_bounds__(1024) void fin_kernel(const float* __restrict__ part,
                                                   float* __restrict__ out, int nrows) {
    __shared__ float col[4][256];
    __shared__ float ws_s[4], ws_q[4];
    const int t = threadIdx.x;
    const int c = t & 255;
    const int g = t >> 8;

    float a = 0.0f;
    if (c < NDAYS) {
        #pragma unroll 8
        for (int r = g; r < nrows; r += 4) a += part[(size_t)r * NDAYS + c];
    }
    col[g][c] = a;
    __syncthreads();

    float s = 0.0f, q = 0.0f;
    if (t < 256) {
        const float pc = col[0][t] + col[1][t] + col[2][t] + col[3][t];
        if (t < NDAYS) { s = pc; q = pc * pc; }
    }
    #pragma unroll
    for (int off = 32; off > 0; off >>= 1) {
        s += __shfl_down(s, off);
        q += __shfl_down(q, off);
    }
    if (t < 256 && (t & 63) == 0) {
        ws_s[t >> 6] = s;
        ws_q[t >> 6] = q;
    }
    __syncthreads();
    if (t == 0) {
        const float sumPi  = ws_s[0] + ws_s[1] + ws_s[2] + ws_s[3];
        const float sumPi2 = ws_q[0] + ws_q[1] + ws_q[2] + ws_q[3];
        out[0] = -1.0f * sumPi * fmaxf(sumPi, 0.0f) / sumPi2 / (float)NDAYS;
    }
}

extern "C" void kernel_launch(void* const* d_in, const int* in_sizes, int n_in,
                              void* d_out, int out_size, void* d_ws, size_t ws_size,
                              hipStream_t stream) {
    const float* inputs  = (const float*)d_in[0];
    const float* targets = (const float*)d_in[1];
    const float* weights = (const float*)d_in[2];
    const int*   date    = (const int*)d_in[3];
    float* out  = (float*)d_out;
    float* part = (float*)d_ws;                 // up to MAXROWS*NDAYS floats = 512 KB

    const int n  = in_sizes[2];                 // N (weights is [N])
    const int nq = n >> 2;
    const int grid = (nq + TILE - 1) / TILE;    // 489 for N=2M

    pi_kernel<<<grid, TPB, 0, stream>>>(inputs, targets, weights, date, part, n);
    fin_kernel<<<1, 1024, 0, stream>>>(part, out, grid);
}